// Round 1
// baseline (310.423 us; speedup 1.0000x reference)
//
#include <hip/hip_runtime.h>

// AttentionSampling: out[b,s,:] = q[b,s,:] + sum_f dot(LN(q)[b,s,:], LN(k)[b,4s+f,:]) * LN(v)[b,4s+f,:]
// B=4, Sq=2048, Skv=8192, D=1024, fp32. Fully fused single-pass kernel:
// each input byte is read exactly once -> memory-roofline-bound (~324 MB total traffic).

constexpr int D      = 1024;
constexpr int FACTOR = 4;
constexpr int BLOCK  = 256;           // 4 waves; each thread owns 4 contiguous floats
constexpr int NW     = BLOCK / 64;    // waves per block
constexpr float EPS  = 1e-5f;

__device__ __forceinline__ float wave_reduce_sum(float x) {
#pragma unroll
    for (int off = 32; off > 0; off >>= 1)
        x += __shfl_down(x, off, 64);
    return x;
}

// Reduce N per-thread values to block-wide sums, broadcast to all threads.
template <int N>
__device__ __forceinline__ void block_reduce(float* vals, float* s_buf) {
    const int lane = threadIdx.x & 63;
    const int wave = threadIdx.x >> 6;
#pragma unroll
    for (int i = 0; i < N; i++) {
        float x = wave_reduce_sum(vals[i]);
        if (lane == 0) s_buf[wave * N + i] = x;
    }
    __syncthreads();
#pragma unroll
    for (int i = 0; i < N; i++) {
        float t = 0.f;
#pragma unroll
        for (int w = 0; w < NW; w++) t += s_buf[w * N + i];
        vals[i] = t;
    }
    __syncthreads();  // allow safe reuse of s_buf
}

__device__ __forceinline__ float4 ln4(float4 x, float mu, float rs, float4 w, float4 b) {
    float4 r;
    r.x = (x.x - mu) * rs * w.x + b.x;
    r.y = (x.y - mu) * rs * w.y + b.y;
    r.z = (x.z - mu) * rs * w.z + b.z;
    r.w = (x.w - mu) * rs * w.w + b.w;
    return r;
}

__device__ __forceinline__ float dot4(float4 a, float4 b) {
    return a.x * b.x + a.y * b.y + a.z * b.z + a.w * b.w;
}

__global__ __launch_bounds__(BLOCK) void attn_ds_kernel(
    const float* __restrict__ q,    // [B*Sq, D]
    const float* __restrict__ k,    // [B*Skv, D] = [B*Sq*4, D]
    const float* __restrict__ v,    // [B*Skv, D]
    const float* __restrict__ lw,   // [D]
    const float* __restrict__ lb,   // [D]
    float* __restrict__ out)        // [B*Sq, D]
{
    __shared__ float s_buf[NW * 18];

    const size_t row = blockIdx.x;           // b*Sq + s
    const int tid = threadIdx.x;
    const int d0  = tid * 4;                 // this thread's 4 floats within D

    // ---- load everything up-front (independent loads -> latency hiding) ----
    const float4 qv = *(const float4*)(q + row * D + d0);
    float4 kv[FACTOR], vv[FACTOR];
#pragma unroll
    for (int f = 0; f < FACTOR; f++) {
        kv[f] = *(const float4*)(k + (row * FACTOR + f) * (size_t)D + d0);
        vv[f] = *(const float4*)(v + (row * FACTOR + f) * (size_t)D + d0);
    }
    const float4 wv = *(const float4*)(lw + d0);
    const float4 bv = *(const float4*)(lb + d0);

    // ---- phase 1: sum & sumsq for q row, 4 k rows, 4 v rows (18 values) ----
    float red[18];
    red[0] = qv.x + qv.y + qv.z + qv.w;
    red[1] = qv.x * qv.x + qv.y * qv.y + qv.z * qv.z + qv.w * qv.w;
#pragma unroll
    for (int f = 0; f < FACTOR; f++) {
        red[2 + 2 * f]  = kv[f].x + kv[f].y + kv[f].z + kv[f].w;
        red[3 + 2 * f]  = kv[f].x * kv[f].x + kv[f].y * kv[f].y + kv[f].z * kv[f].z + kv[f].w * kv[f].w;
        red[10 + 2 * f] = vv[f].x + vv[f].y + vv[f].z + vv[f].w;
        red[11 + 2 * f] = vv[f].x * vv[f].x + vv[f].y * vv[f].y + vv[f].z * vv[f].z + vv[f].w * vv[f].w;
    }
    block_reduce<18>(red, s_buf);

    const float invD = 1.0f / (float)D;
    const float mu_q = red[0] * invD;
    const float rs_q = rsqrtf(red[1] * invD - mu_q * mu_q + EPS);
    float mu_k[FACTOR], rs_k[FACTOR], mu_v[FACTOR], rs_v[FACTOR];
#pragma unroll
    for (int f = 0; f < FACTOR; f++) {
        mu_k[f] = red[2 + 2 * f] * invD;
        rs_k[f] = rsqrtf(red[3 + 2 * f] * invD - mu_k[f] * mu_k[f] + EPS);
        mu_v[f] = red[10 + 2 * f] * invD;
        rs_v[f] = rsqrtf(red[11 + 2 * f] * invD - mu_v[f] * mu_v[f] + EPS);
    }

    // ---- phase 2: dot(qn, kn_f) for the 4 window positions ----
    const float4 qn = ln4(qv, mu_q, rs_q, wv, bv);
    float dp[FACTOR];
#pragma unroll
    for (int f = 0; f < FACTOR; f++) {
        const float4 kn = ln4(kv[f], mu_k[f], rs_k[f], wv, bv);
        dp[f] = dot4(qn, kn);
    }
    block_reduce<FACTOR>(dp, s_buf);

    // ---- epilogue: out = q + sum_f dp[f] * vn_f ----
    float4 acc = qv;
#pragma unroll
    for (int f = 0; f < FACTOR; f++) {
        const float4 vn = ln4(vv[f], mu_v[f], rs_v[f], wv, bv);
        acc.x += dp[f] * vn.x;
        acc.y += dp[f] * vn.y;
        acc.z += dp[f] * vn.z;
        acc.w += dp[f] * vn.w;
    }
    *(float4*)(out + row * D + d0) = acc;
}

extern "C" void kernel_launch(void* const* d_in, const int* in_sizes, int n_in,
                              void* d_out, int out_size, void* d_ws, size_t ws_size,
                              hipStream_t stream) {
    const float* q  = (const float*)d_in[0];
    const float* k  = (const float*)d_in[1];
    const float* v  = (const float*)d_in[2];
    const float* lw = (const float*)d_in[3];
    const float* lb = (const float*)d_in[4];
    float* out = (float*)d_out;

    const int rows = in_sizes[0] / D;  // B * Sq = 8192
    attn_ds_kernel<<<dim3(rows), dim3(BLOCK), 0, stream>>>(q, k, v, lw, lb, out);
}

// Round 2
// 310.228 us; speedup vs baseline: 1.0006x; 1.0006x over previous
//
#include <hip/hip_runtime.h>

// AttentionSampling: out[b,s,:] = q[b,s,:] + sum_f dot(LN(q)[b,s,:], LN(k)[b,4s+f,:]) * LN(v)[b,4s+f,:]
// B=4, Sq=2048, Skv=8192, D=1024, fp32.
//
// R2 design: ONE WAVE PER OUTPUT ROW. Zero LDS, zero barriers, zero DS-pipe ops:
// all cross-lane reductions use DPP (row_shr 1/2/4/8 + row_bcast 15/31) on the
// VALU pipe, broadcast via v_readlane. dot(qn, kn) is algebraically expanded into
// phase-1 sums (Σqk·w², Σk·w², Σk·wb, ...) so the k registers die before v is
// loaded -> peak VGPR stays ~3 waves/SIMD. Lane L owns elements {c*256 + L*4 ..+4},
// c=0..3 -> every global access is a fully-coalesced dwordx4.

constexpr int D     = 1024;
constexpr int BLOCK = 256;           // 4 independent waves per block
constexpr float EPS = 1e-5f;

template<int CTRL>
__device__ __forceinline__ float dpp_add(float x) {
    int xi = __builtin_bit_cast(int, x);
    int yi = __builtin_amdgcn_update_dpp(0, xi, CTRL, 0xF, 0xF, true);
    return x + __builtin_bit_cast(float, yi);
}

// Full wave64 sum, entirely on the VALU pipe. Valid total lands in lane 63,
// broadcast to all lanes (as an SGPR) via readlane.
__device__ __forceinline__ float wave_sum(float x) {
    x = dpp_add<0x111>(x);   // row_shr:1
    x = dpp_add<0x112>(x);   // row_shr:2
    x = dpp_add<0x114>(x);   // row_shr:4
    x = dpp_add<0x118>(x);   // row_shr:8  -> lane 16r+15 = row sum
    x = dpp_add<0x142>(x);   // row_bcast:15
    x = dpp_add<0x143>(x);   // row_bcast:31 -> lane 63 = wave sum
    return __builtin_bit_cast(float, __builtin_amdgcn_readlane(__builtin_bit_cast(int, x), 63));
}

__global__ __launch_bounds__(BLOCK, 3) void attn_ds_kernel(
    const float* __restrict__ q,    // [B*Sq, D]
    const float* __restrict__ k,    // [B*Sq*4, D]
    const float* __restrict__ v,    // [B*Sq*4, D]
    const float* __restrict__ lw,   // [D]
    const float* __restrict__ lb,   // [D]
    float* __restrict__ out)        // [B*Sq, D]
{
    const int lane = threadIdx.x & 63;
    const int wid  = threadIdx.x >> 6;
    const long row = (long)blockIdx.x * 4 + wid;   // 0..8191
    const int off0 = lane * 4;

    const float* qp = q + row * D;
    const float* kp = k + row * (4L * D);
    const float* vp = v + row * (4L * D);

    // ---- stage 1 loads: q row, 4 k rows, w, b (28 coalesced dwordx4) ----
    float4 qv[4], wv[4], bv[4], kv[4][4];
#pragma unroll
    for (int c = 0; c < 4; c++) {
        const int e = c * 256 + off0;
        qv[c] = *(const float4*)(qp + e);
        wv[c] = *(const float4*)(lw + e);
        bv[c] = *(const float4*)(lb + e);
    }
#pragma unroll
    for (int f = 0; f < 4; f++)
#pragma unroll
        for (int c = 0; c < 4; c++)
            kv[f][c] = *(const float4*)(kp + f * D + c * 256 + off0);

    // ---- phase-1 per-lane partials ----
    float4 qw[4];  // q*w, reused for the 4 cross terms; dies before round 1
    float Sq = 0, Sqq = 0, Sq_w2 = 0, Sq_wb = 0, Sw2 = 0, Swb = 0, Sbb = 0;
#pragma unroll
    for (int c = 0; c < 4; c++) {
#define ACCQ(m) { \
        float qe = qv[c].m, we = wv[c].m, be = bv[c].m; \
        float qwe = qe * we; qw[c].m = qwe; \
        Sq += qe; Sqq = fmaf(qe, qe, Sqq); \
        Sq_w2 = fmaf(qwe, we, Sq_w2); Sq_wb = fmaf(qwe, be, Sq_wb); \
        Sw2 = fmaf(we, we, Sw2); Swb = fmaf(we, be, Swb); Sbb = fmaf(be, be, Sbb); }
        ACCQ(x) ACCQ(y) ACCQ(z) ACCQ(w)
#undef ACCQ
    }

    float Sk[4], Skk[4], Sk_w2[4], Sk_wb[4], Sqk[4];
#pragma unroll
    for (int f = 0; f < 4; f++) {
        float s0 = 0, s1 = 0, s2 = 0, s3 = 0, s4 = 0;
#pragma unroll
        for (int c = 0; c < 4; c++) {
#define ACCK(m) { \
            float ke = kv[f][c].m, we = wv[c].m, be = bv[c].m; \
            float kwe = ke * we; \
            s0 += ke; s1 = fmaf(ke, ke, s1); \
            s2 = fmaf(kwe, we, s2); s3 = fmaf(kwe, be, s3); \
            s4 = fmaf(qw[c].m, kwe, s4); }
            ACCK(x) ACCK(y) ACCK(z) ACCK(w)
#undef ACCK
        }
        Sk[f] = s0; Skk[f] = s1; Sk_w2[f] = s2; Sk_wb[f] = s3; Sqk[f] = s4;
    }

    // ---- round 1: 27 DPP reductions (k registers are dead now) ----
    Sq = wave_sum(Sq);   Sqq = wave_sum(Sqq);
    Sq_w2 = wave_sum(Sq_w2); Sq_wb = wave_sum(Sq_wb);
    Sw2 = wave_sum(Sw2); Swb = wave_sum(Swb); Sbb = wave_sum(Sbb);
#pragma unroll
    for (int f = 0; f < 4; f++) {
        Sk[f] = wave_sum(Sk[f]);       Skk[f] = wave_sum(Skk[f]);
        Sk_w2[f] = wave_sum(Sk_w2[f]); Sk_wb[f] = wave_sum(Sk_wb[f]);
        Sqk[f] = wave_sum(Sqk[f]);
    }

    // ---- issue v loads now (fence keeps them from being hoisted up) ----
    asm volatile("" ::: "memory");
    float4 vv[4][4];
#pragma unroll
    for (int f = 0; f < 4; f++)
#pragma unroll
        for (int c = 0; c < 4; c++)
            vv[f][c] = *(const float4*)(vp + f * D + c * 256 + off0);

    // ---- dp[f] from reduced scalars (uniform math, overlaps v latency) ----
    const float invD = 1.0f / (float)D;
    const float mu_q = Sq * invD;
    const float rs_q = rsqrtf(fmaf(-mu_q, mu_q, Sqq * invD) + EPS);
    const float qwb_c = Sq_wb - mu_q * Swb;
    float dp[4];
#pragma unroll
    for (int f = 0; f < 4; f++) {
        float mu_k = Sk[f] * invD;
        float rs_k = rsqrtf(fmaf(-mu_k, mu_k, Skk[f] * invD) + EPS);
        float cross = Sqk[f] - mu_q * Sk_w2[f] - mu_k * Sq_w2 + mu_q * mu_k * Sw2;
        dp[f] = rs_q * rs_k * cross + rs_q * qwb_c + rs_k * (Sk_wb[f] - mu_k * Swb) + Sbb;
    }

    // ---- v stats + round 2 (8 DPP reductions) ----
    float Sv[4], Svv[4];
#pragma unroll
    for (int f = 0; f < 4; f++) {
        float s0 = 0, s1 = 0;
#pragma unroll
        for (int c = 0; c < 4; c++) {
#define ACCV(m) { float ve = vv[f][c].m; s0 += ve; s1 = fmaf(ve, ve, s1); }
            ACCV(x) ACCV(y) ACCV(z) ACCV(w)
#undef ACCV
        }
        Sv[f] = wave_sum(s0); Svv[f] = wave_sum(s1);
    }

    // ---- epilogue: out = q + sum_f dp[f] * LN(v_f) ----
    float4 acc[4];
#pragma unroll
    for (int c = 0; c < 4; c++) acc[c] = qv[c];
#pragma unroll
    for (int f = 0; f < 4; f++) {
        float mu_v = Sv[f] * invD;
        float rs_v = rsqrtf(fmaf(-mu_v, mu_v, Svv[f] * invD) + EPS);
        float av = rs_v, cv = -mu_v * rs_v;
        float dpf = dp[f];
#pragma unroll
        for (int c = 0; c < 4; c++) {
#define ACCO(m) { \
            float t = fmaf(av, vv[f][c].m, cv); \
            float vn = fmaf(t, wv[c].m, bv[c].m); \
            acc[c].m = fmaf(dpf, vn, acc[c].m); }
            ACCO(x) ACCO(y) ACCO(z) ACCO(w)
#undef ACCO
        }
    }
#pragma unroll
    for (int c = 0; c < 4; c++)
        *(float4*)(out + row * D + c * 256 + off0) = acc[c];
}

extern "C" void kernel_launch(void* const* d_in, const int* in_sizes, int n_in,
                              void* d_out, int out_size, void* d_ws, size_t ws_size,
                              hipStream_t stream) {
    const float* q  = (const float*)d_in[0];
    const float* k  = (const float*)d_in[1];
    const float* v  = (const float*)d_in[2];
    const float* lw = (const float*)d_in[3];
    const float* lb = (const float*)d_in[4];
    float* out = (float*)d_out;

    const int rows = in_sizes[0] / D;          // B*Sq = 8192
    attn_ds_kernel<<<dim3(rows / 4), dim3(BLOCK), 0, stream>>>(q, k, v, lw, lb, out);
}